// Round 1
// baseline (1050.341 us; speedup 1.0000x reference)
//
#include <hip/hip_runtime.h>

// MoE top-2, E=8, D=1024, F=4096, T=4096 tokens, fp32 in/out.
// Pipeline: gate(+x->bf16) -> offsets -> fill lists -> fused SwiGLU GEMM1 (bf16 MFMA)
//           -> GEMM2 with atomicAdd scatter epilogue.

#define T_TOK 4096
#define DM    1024
#define FF    4096
#define NE    8

#define BM 128
#define BN 128
#define BK 32
#define BS 36   // transposed B-tile LDS stride (elements): 72B rows -> 8B-aligned b64 frags, ~4-way write conflicts

typedef unsigned short u16;
typedef short short8 __attribute__((ext_vector_type(8)));
typedef float floatx4 __attribute__((ext_vector_type(4)));

// ws layout (bytes)
#define WS_COUNTS  0u
#define WS_CURS    32u
#define WS_OFFS    64u
#define WS_SEL     4096u
#define WS_SELW    (4096u + 32768u)
#define WS_STOK    (4096u + 65536u)
#define WS_SW      (4096u + 98304u)
#define WS_XBF     (1u << 20)
#define WS_HBUF    ((1u << 20) + (8u << 20))

__device__ __forceinline__ u16 f2bf(float f) {
  union { float f; unsigned int u; } v; v.f = f;
  unsigned int r = v.u + 0x7fffu + ((v.u >> 16) & 1u);  // RNE
  return (u16)(r >> 16);
}

__device__ __forceinline__ short8 ld_b_frag(const u16* p) {
  // 8 bf16 from LDS, only 8B-aligned (stride-36 rows) -> 2x b64
  union { unsigned long long q[2]; short8 v; } r;
  r.q[0] = *(const unsigned long long*)(p);
  r.q[1] = *(const unsigned long long*)(p + 4);
  return r.v;
}

// ---------------- gate: logits (double accum), top2+softmax, x->bf16 ----------------
__global__ __launch_bounds__(256) void gate_kernel(
    const float* __restrict__ x, const float* __restrict__ gw,
    u16* __restrict__ xbf, int* __restrict__ sel, float* __restrict__ selw,
    int* __restrict__ counts)
{
  const int t = blockIdx.x * 4 + (threadIdx.x >> 6);   // one wave per token
  const int lane = threadIdx.x & 63;
  const float* xr = x + (size_t)t * DM;
  double acc[NE];
#pragma unroll
  for (int e = 0; e < NE; ++e) acc[e] = 0.0;
#pragma unroll 4
  for (int i = 0; i < 16; ++i) {
    const int d = i * 64 + lane;
    const float xv = xr[d];
    xbf[(size_t)t * DM + d] = f2bf(xv);
    const float4* g = (const float4*)(gw + (size_t)d * NE);
    float4 g0 = g[0], g1 = g[1];
    acc[0] += (double)xv * g0.x; acc[1] += (double)xv * g0.y;
    acc[2] += (double)xv * g0.z; acc[3] += (double)xv * g0.w;
    acc[4] += (double)xv * g1.x; acc[5] += (double)xv * g1.y;
    acc[6] += (double)xv * g1.z; acc[7] += (double)xv * g1.w;
  }
#pragma unroll
  for (int off = 32; off >= 1; off >>= 1) {
#pragma unroll
    for (int e = 0; e < NE; ++e) acc[e] += __shfl_xor(acc[e], off, 64);
  }
  if (lane == 0) {
    int i1 = 0; double v1 = acc[0];
#pragma unroll
    for (int e = 1; e < NE; ++e) if (acc[e] > v1) { v1 = acc[e]; i1 = e; }
    int i2 = -1; double v2 = -1e300;
#pragma unroll
    for (int e = 0; e < NE; ++e) if (e != i1 && acc[e] > v2) { v2 = acc[e]; i2 = e; }
    float p1 = 1.0f / (1.0f + expf((float)(v2 - v1)));   // exact 2-way softmax
    sel[t * 2] = i1; sel[t * 2 + 1] = i2;
    selw[t * 2] = p1; selw[t * 2 + 1] = 1.0f - p1;
    atomicAdd(&counts[i1], 1);
    atomicAdd(&counts[i2], 1);
  }
}

__global__ void offsets_kernel(const int* __restrict__ counts, int* __restrict__ offsets) {
  if (threadIdx.x == 0) {
    int s = 0;
#pragma unroll
    for (int e = 0; e < NE; ++e) { offsets[e] = s; s += counts[e]; }
  }
}

__global__ void fill_kernel(const int* __restrict__ sel, const float* __restrict__ selw,
                            const int* __restrict__ offsets, int* __restrict__ cursors,
                            int* __restrict__ stok, float* __restrict__ sw)
{
  const int t = blockIdx.x * blockDim.x + threadIdx.x;
  if (t >= T_TOK) return;
#pragma unroll
  for (int k = 0; k < 2; ++k) {
    int e = sel[t * 2 + k];
    int pos = atomicAdd(&cursors[e], 1);
    int p = offsets[e] + pos;
    stok[p] = t;
    sw[p] = selw[t * 2 + k];
  }
}

// ---------------- GEMM1: H = silu(Xg*W1) .* (Xg*W3), bf16 MFMA ----------------
__global__ __launch_bounds__(256, 2) void gemm1_kernel(
    const u16* __restrict__ xbf, const float* __restrict__ w1, const float* __restrict__ w3,
    const int* __restrict__ stok, const int* __restrict__ offsets,
    const int* __restrict__ counts, u16* __restrict__ Hbuf)
{
  const int e  = blockIdx.z;
  const int mt = blockIdx.y;
  const int ne = counts[e];
  if (mt * BM >= ne) return;
  const int nt = blockIdx.x;
  const int base = offsets[e];
  const float* __restrict__ W1 = w1 + (size_t)e * DM * FF;
  const float* __restrict__ W3 = w3 + (size_t)e * DM * FF;

  __shared__ u16 Al[BM][BK];
  __shared__ u16 B1l[BN][BS];
  __shared__ u16 B3l[BN][BS];

  const int tid  = threadIdx.x;
  const int lane = tid & 63;
  const int wv   = tid >> 6;
  const int wm   = (wv & 1) * 64;
  const int wn   = (wv >> 1) * 64;
  const int ln15 = lane & 15;
  const int q    = lane >> 4;

  // A staging map: 2 threads/row, 16 bf16 each (token gather)
  const int arow = tid >> 1;
  const int aseg = (tid & 1) * 16;
  const int rg_a = mt * BM + arow;
  const u16* asrc = nullptr;
  if (rg_a < ne) {
    int tok = stok[base + rg_a];
    asrc = xbf + (size_t)tok * DM + aseg;
  }

  // B staging map: column nb, 16 k-rows, scalar fp32 loads (lane-coalesced), cvt->bf16, b64 LDS writes
  const int nb = tid & 127;
  const int kh = (tid >> 7) * 16;
  const int n0 = nt * BN;
  const float* b1p = W1 + (size_t)kh * FF + n0 + nb;
  const float* b3p = W3 + (size_t)kh * FF + n0 + nb;

  floatx4 acc1[4][4], acc3[4][4];
#pragma unroll
  for (int mi = 0; mi < 4; ++mi)
#pragma unroll
    for (int ni = 0; ni < 4; ++ni) {
      acc1[mi][ni] = (floatx4){0.f, 0.f, 0.f, 0.f};
      acc3[mi][ni] = (floatx4){0.f, 0.f, 0.f, 0.f};
    }

  for (int kc = 0; kc < DM; kc += BK) {
    if (asrc) {
      const uint4* s = (const uint4*)(asrc + kc);
      *(uint4*)&Al[arow][aseg]     = s[0];
      *(uint4*)&Al[arow][aseg + 8] = s[1];
    } else {
      uint4 z = {0u, 0u, 0u, 0u};
      *(uint4*)&Al[arow][aseg]     = z;
      *(uint4*)&Al[arow][aseg + 8] = z;
    }
    const float* p1 = b1p + (size_t)kc * FF;
    const float* p3 = b3p + (size_t)kc * FF;
#pragma unroll
    for (int kk = 0; kk < 16; kk += 4) {
      union { u16 s[4]; uint2 u; } v1, v3;
#pragma unroll
      for (int j = 0; j < 4; ++j) {
        v1.s[j] = f2bf(p1[(size_t)(kk + j) * FF]);
        v3.s[j] = f2bf(p3[(size_t)(kk + j) * FF]);
      }
      *(uint2*)&B1l[nb][kh + kk] = v1.u;
      *(uint2*)&B3l[nb][kh + kk] = v3.u;
    }
    __syncthreads();

    short8 af[4];
#pragma unroll
    for (int mi = 0; mi < 4; ++mi)
      af[mi] = *(const short8*)&Al[wm + mi * 16 + ln15][q * 8];
#pragma unroll
    for (int ni = 0; ni < 4; ++ni) {
      short8 b1 = ld_b_frag(&B1l[wn + ni * 16 + ln15][q * 8]);
      short8 b3 = ld_b_frag(&B3l[wn + ni * 16 + ln15][q * 8]);
#pragma unroll
      for (int mi = 0; mi < 4; ++mi) {
        acc1[mi][ni] = __builtin_amdgcn_mfma_f32_16x16x32_bf16(af[mi], b1, acc1[mi][ni], 0, 0, 0);
        acc3[mi][ni] = __builtin_amdgcn_mfma_f32_16x16x32_bf16(af[mi], b3, acc3[mi][ni], 0, 0, 0);
      }
    }
    __syncthreads();
  }

  // epilogue: h = silu(a1)*a3 -> bf16 H rows (C/D layout: row = q*4+reg, col = lane&15)
#pragma unroll
  for (int mi = 0; mi < 4; ++mi) {
#pragma unroll
    for (int reg = 0; reg < 4; ++reg) {
      int rg = mt * BM + wm + mi * 16 + q * 4 + reg;
      if (rg < ne) {
        u16* dst = Hbuf + (size_t)(base + rg) * FF + n0 + wn + ln15;
#pragma unroll
        for (int ni = 0; ni < 4; ++ni) {
          float a = acc1[mi][ni][reg];
          float b = acc3[mi][ni][reg];
          float h = (a / (1.0f + __expf(-a))) * b;
          dst[ni * 16] = f2bf(h);
        }
      }
    }
  }
}

// ---------------- GEMM2: Y = H*W2, scatter-add epilogue ----------------
__global__ __launch_bounds__(256, 2) void gemm2_kernel(
    const u16* __restrict__ Hbuf, const float* __restrict__ w2,
    const int* __restrict__ stok, const float* __restrict__ sw,
    const int* __restrict__ offsets, const int* __restrict__ counts,
    float* __restrict__ out)
{
  const int e  = blockIdx.z;
  const int mt = blockIdx.y;
  const int ne = counts[e];
  if (mt * BM >= ne) return;
  const int nt = blockIdx.x;
  const int base = offsets[e];
  const float* __restrict__ W2 = w2 + (size_t)e * FF * DM;

  __shared__ u16 Al[BM][BK];
  __shared__ u16 Bl[BN][BS];

  const int tid  = threadIdx.x;
  const int lane = tid & 63;
  const int wv   = tid >> 6;
  const int wm   = (wv & 1) * 64;
  const int wn   = (wv >> 1) * 64;
  const int ln15 = lane & 15;
  const int q    = lane >> 4;

  const int arow = tid >> 1;
  const int aseg = (tid & 1) * 16;
  const int rg_a = mt * BM + arow;
  const u16* asrc = nullptr;
  if (rg_a < ne) asrc = Hbuf + (size_t)(base + rg_a) * FF + aseg;

  const int nb = tid & 127;
  const int kh = (tid >> 7) * 16;
  const int n0 = nt * BN;
  const float* bp = W2 + (size_t)kh * DM + n0 + nb;

  floatx4 acc[4][4];
#pragma unroll
  for (int mi = 0; mi < 4; ++mi)
#pragma unroll
    for (int ni = 0; ni < 4; ++ni) acc[mi][ni] = (floatx4){0.f, 0.f, 0.f, 0.f};

  for (int kc = 0; kc < FF; kc += BK) {
    if (asrc) {
      const uint4* s = (const uint4*)(asrc + kc);
      *(uint4*)&Al[arow][aseg]     = s[0];
      *(uint4*)&Al[arow][aseg + 8] = s[1];
    } else {
      uint4 z = {0u, 0u, 0u, 0u};
      *(uint4*)&Al[arow][aseg]     = z;
      *(uint4*)&Al[arow][aseg + 8] = z;
    }
    const float* p2 = bp + (size_t)kc * DM;
#pragma unroll
    for (int kk = 0; kk < 16; kk += 4) {
      union { u16 s[4]; uint2 u; } v2;
#pragma unroll
      for (int j = 0; j < 4; ++j) v2.s[j] = f2bf(p2[(size_t)(kk + j) * DM]);
      *(uint2*)&Bl[nb][kh + kk] = v2.u;
    }
    __syncthreads();

    short8 af[4];
#pragma unroll
    for (int mi = 0; mi < 4; ++mi)
      af[mi] = *(const short8*)&Al[wm + mi * 16 + ln15][q * 8];
#pragma unroll
    for (int ni = 0; ni < 4; ++ni) {
      short8 b = ld_b_frag(&Bl[wn + ni * 16 + ln15][q * 8]);
#pragma unroll
      for (int mi = 0; mi < 4; ++mi)
        acc[mi][ni] = __builtin_amdgcn_mfma_f32_16x16x32_bf16(af[mi], b, acc[mi][ni], 0, 0, 0);
    }
    __syncthreads();
  }

#pragma unroll
  for (int mi = 0; mi < 4; ++mi) {
#pragma unroll
    for (int reg = 0; reg < 4; ++reg) {
      int rg = mt * BM + wm + mi * 16 + q * 4 + reg;
      if (rg < ne) {
        int p = base + rg;
        int tok = stok[p];
        float wgt = sw[p];
        float* dst = out + (size_t)tok * DM + n0 + wn + ln15;
#pragma unroll
        for (int ni = 0; ni < 4; ++ni)
          atomicAdd(&dst[ni * 16], wgt * acc[mi][ni][reg]);
      }
    }
  }
}

extern "C" void kernel_launch(void* const* d_in, const int* in_sizes, int n_in,
                              void* d_out, int out_size, void* d_ws, size_t ws_size,
                              hipStream_t stream) {
  const float* x  = (const float*)d_in[0];
  const float* gw = (const float*)d_in[1];
  const float* w1 = (const float*)d_in[2];
  const float* w2 = (const float*)d_in[3];
  const float* w3 = (const float*)d_in[4];
  float* out = (float*)d_out;
  char* ws = (char*)d_ws;

  int*   counts  = (int*)(ws + WS_COUNTS);
  int*   cursors = (int*)(ws + WS_CURS);
  int*   offsets = (int*)(ws + WS_OFFS);
  int*   sel     = (int*)(ws + WS_SEL);
  float* selw    = (float*)(ws + WS_SELW);
  int*   stok    = (int*)(ws + WS_STOK);
  float* sw      = (float*)(ws + WS_SW);
  u16*   xbf     = (u16*)(ws + WS_XBF);
  u16*   Hbuf    = (u16*)(ws + WS_HBUF);

  size_t need = (size_t)WS_HBUF + (size_t)(T_TOK * 2) * FF * 2;  // ~76.5 MB
  if (ws_size < need) return;  // ws too small: bail (will show as wrong-answer)

  hipMemsetAsync(ws, 0, 96, stream);                                    // counts+cursors
  hipMemsetAsync(d_out, 0, (size_t)T_TOK * DM * sizeof(float), stream); // atomic target

  gate_kernel<<<T_TOK / 4, 256, 0, stream>>>(x, gw, xbf, sel, selw, counts);
  offsets_kernel<<<1, 64, 0, stream>>>(counts, offsets);
  fill_kernel<<<T_TOK / 256, 256, 0, stream>>>(sel, selw, offsets, cursors, stok, sw);
  gemm1_kernel<<<dim3(FF / BN, T_TOK / BM, NE), 256, 0, stream>>>(xbf, w1, w3, stok, offsets, counts, Hbuf);
  gemm2_kernel<<<dim3(DM / BN, T_TOK / BM, NE), 256, 0, stream>>>(Hbuf, w2, stok, sw, offsets, counts, out);
}

// Round 2
// 925.500 us; speedup vs baseline: 1.1349x; 1.1349x over previous
//
#include <hip/hip_runtime.h>

// MoE top-2, E=8, D=1024, F=4096, T=4096 tokens, fp32 in/out.
// R2: preconvert weights fp32[k][n] -> bf16[n][k] (transposed), then m97-style
// GEMMs with global_load_lds(16B) staging + ds_read_b128 fragments.
// Fallback to R1 fused-convert path if ws_size < 265 MB.

#define T_TOK 4096
#define DM    1024
#define FF    4096
#define NE    8

#define BM 128
#define BN 128
#define BK 32
#define BS 36   // R1 fallback transposed B stride

typedef unsigned short u16;
typedef short short8 __attribute__((ext_vector_type(8)));
typedef float floatx4 __attribute__((ext_vector_type(4)));

// ---- ws layout (bytes) ----
// common small region
#define WS_COUNTS  0u
#define WS_CURS    32u
#define WS_OFFS    64u
#define WS_SEL     4096u
#define WS_SELW    (4096u + 32768u)
#define WS_STOK    (4096u + 65536u)
#define WS_SW      (4096u + 98304u)
#define WS_XBF     ((size_t)1 << 20)
#define WS_HBUF    ((size_t)9 << 20)       // 64 MB (8192 x 4096 bf16)
// new-path extra
#define WS_WT1     ((size_t)73 << 20)      // 64 MB bf16 [E][F][D]
#define WS_WT3     ((size_t)137 << 20)
#define WS_WT2     ((size_t)201 << 20)     // 64 MB bf16 [E][D][F]

__device__ __forceinline__ u16 f2bf(float f) {
  union { float f; unsigned int u; } v; v.f = f;
  unsigned int r = v.u + 0x7fffu + ((v.u >> 16) & 1u);  // RNE
  return (u16)(r >> 16);
}

__device__ __forceinline__ void async16(u16* lds, const u16* g) {
  // one wave-instruction: lane i's 16B -> lds_base + i*16 (lds must be wave-uniform)
  __builtin_amdgcn_global_load_lds(
      (const __attribute__((address_space(1))) unsigned int*)g,
      (__attribute__((address_space(3))) unsigned int*)lds, 16, 0, 0);
}

__device__ __forceinline__ short8 ld_b_frag(const u16* p) {
  union { unsigned long long q[2]; short8 v; } r;
  r.q[0] = *(const unsigned long long*)(p);
  r.q[1] = *(const unsigned long long*)(p + 4);
  return r.v;
}

// ---------------- gate: logits (double accum), top2+softmax, x->bf16 ----------------
__global__ __launch_bounds__(256) void gate_kernel(
    const float* __restrict__ x, const float* __restrict__ gw,
    u16* __restrict__ xbf, int* __restrict__ sel, float* __restrict__ selw,
    int* __restrict__ counts)
{
  const int t = blockIdx.x * 4 + (threadIdx.x >> 6);   // one wave per token
  const int lane = threadIdx.x & 63;
  const float* xr = x + (size_t)t * DM;
  double acc[NE];
#pragma unroll
  for (int e = 0; e < NE; ++e) acc[e] = 0.0;
#pragma unroll 4
  for (int i = 0; i < 16; ++i) {
    const int d = i * 64 + lane;
    const float xv = xr[d];
    xbf[(size_t)t * DM + d] = f2bf(xv);
    const float4* g = (const float4*)(gw + (size_t)d * NE);
    float4 g0 = g[0], g1 = g[1];
    acc[0] += (double)xv * g0.x; acc[1] += (double)xv * g0.y;
    acc[2] += (double)xv * g0.z; acc[3] += (double)xv * g0.w;
    acc[4] += (double)xv * g1.x; acc[5] += (double)xv * g1.y;
    acc[6] += (double)xv * g1.z; acc[7] += (double)xv * g1.w;
  }
#pragma unroll
  for (int off = 32; off >= 1; off >>= 1) {
#pragma unroll
    for (int e = 0; e < NE; ++e) acc[e] += __shfl_xor(acc[e], off, 64);
  }
  if (lane == 0) {
    int i1 = 0; double v1 = acc[0];
#pragma unroll
    for (int e = 1; e < NE; ++e) if (acc[e] > v1) { v1 = acc[e]; i1 = e; }
    int i2 = -1; double v2 = -1e300;
#pragma unroll
    for (int e = 0; e < NE; ++e) if (e != i1 && acc[e] > v2) { v2 = acc[e]; i2 = e; }
    float p1 = 1.0f / (1.0f + expf((float)(v2 - v1)));   // exact 2-way softmax
    sel[t * 2] = i1; sel[t * 2 + 1] = i2;
    selw[t * 2] = p1; selw[t * 2 + 1] = 1.0f - p1;
    atomicAdd(&counts[i1], 1);
    atomicAdd(&counts[i2], 1);
  }
}

__global__ void offsets_kernel(const int* __restrict__ counts, int* __restrict__ offsets) {
  if (threadIdx.x == 0) {
    int s = 0;
#pragma unroll
    for (int e = 0; e < NE; ++e) { offsets[e] = s; s += counts[e]; }
  }
}

__global__ void fill_kernel(const int* __restrict__ sel, const float* __restrict__ selw,
                            const int* __restrict__ offsets, int* __restrict__ cursors,
                            int* __restrict__ stok, float* __restrict__ sw)
{
  const int t = blockIdx.x * blockDim.x + threadIdx.x;
  if (t >= T_TOK) return;
#pragma unroll
  for (int k = 0; k < 2; ++k) {
    int e = sel[t * 2 + k];
    int pos = atomicAdd(&cursors[e], 1);
    int p = offsets[e] + pos;
    stok[p] = t;
    sw[p] = selw[t * 2 + k];
  }
}

// ---------------- convert+transpose: src fp32 [E][K][N] -> dst bf16 [E][N][K] ----------------
__global__ __launch_bounds__(256) void convt_kernel(const float* __restrict__ src,
                                                    u16* __restrict__ dst, int K, int N)
{
  __shared__ float tile[64][65];
  const int e = blockIdx.z;
  src += (size_t)e * K * N;
  dst += (size_t)e * K * N;
  const int n0 = blockIdx.x * 64;
  const int k0 = blockIdx.y * 64;
  const int tr = threadIdx.x >> 4;          // 0..15
  const int tc = (threadIdx.x & 15) * 4;    // 0..60
#pragma unroll
  for (int i = 0; i < 64; i += 16) {
    const float4 v = *(const float4*)&src[(size_t)(k0 + tr + i) * N + n0 + tc];
    tile[tr + i][tc]     = v.x; tile[tr + i][tc + 1] = v.y;
    tile[tr + i][tc + 2] = v.z; tile[tr + i][tc + 3] = v.w;
  }
  __syncthreads();
#pragma unroll
  for (int i = 0; i < 64; i += 16) {
    union { u16 s[4]; uint2 u; } o;
#pragma unroll
    for (int j = 0; j < 4; ++j) o.s[j] = f2bf(tile[tc + j][tr + i]);
    *(uint2*)&dst[(size_t)(n0 + tr + i) * K + k0 + tc] = o.u;
  }
}

// ---------------- GEMM1 (preconverted): H = silu(Xg*W1t^T).*(Xg*W3t^T) ----------------
__global__ __launch_bounds__(256, 2) void gemm1p_kernel(
    const u16* __restrict__ xbf, const u16* __restrict__ wt1, const u16* __restrict__ wt3,
    const int* __restrict__ stok, const int* __restrict__ offsets,
    const int* __restrict__ counts, u16* __restrict__ Hbuf)
{
  const int e  = blockIdx.z;
  const int mt = blockIdx.y;
  const int ne = counts[e];
  if (mt * BM >= ne) return;
  const int nt = blockIdx.x;
  const int base = offsets[e];
  const u16* __restrict__ W1 = wt1 + (size_t)e * DM * FF;   // [F][D]
  const u16* __restrict__ W3 = wt3 + (size_t)e * DM * FF;

  __shared__ u16 Al[BM * BK];
  __shared__ u16 B1l[BN * BK];
  __shared__ u16 B3l[BN * BK];

  const int tid  = threadIdx.x;
  const int lane = tid & 63;
  const int wv   = tid >> 6;
  const int wm   = (wv & 1) * 64;
  const int wn   = (wv >> 1) * 64;
  const int ln15 = lane & 15;
  const int q    = lane >> 4;
  const int n0   = nt * BN;

  const int rsub = lane >> 2;          // row within a 16-row wave-load
  const int seg  = (lane & 3) * 8;     // bf16 element offset of 16B segment

  const u16* ag[2]; const u16* b1g[2]; const u16* b3g[2];
#pragma unroll
  for (int it = 0; it < 2; ++it) {
    int r  = wv * 32 + it * 16 + rsub;
    int rg = mt * BM + r;
    int p  = base + (rg < ne ? rg : 0);       // clamp OOB rows to a valid row
    int tok = stok[p];
    ag[it]  = xbf + (size_t)tok * DM + seg;
    int n   = n0 + r;
    b1g[it] = W1 + (size_t)n * DM + seg;
    b3g[it] = W3 + (size_t)n * DM + seg;
  }
  u16* al[2]  = { Al  + (wv * 32) * BK, Al  + (wv * 32 + 16) * BK };
  u16* b1l[2] = { B1l + (wv * 32) * BK, B1l + (wv * 32 + 16) * BK };
  u16* b3l[2] = { B3l + (wv * 32) * BK, B3l + (wv * 32 + 16) * BK };

  floatx4 acc1[4][4], acc3[4][4];
#pragma unroll
  for (int mi = 0; mi < 4; ++mi)
#pragma unroll
    for (int ni = 0; ni < 4; ++ni) {
      acc1[mi][ni] = (floatx4){0.f, 0.f, 0.f, 0.f};
      acc3[mi][ni] = (floatx4){0.f, 0.f, 0.f, 0.f};
    }

  for (int kc = 0; kc < DM; kc += BK) {
    async16(al[0],  ag[0]  + kc); async16(al[1],  ag[1]  + kc);
    async16(b1l[0], b1g[0] + kc); async16(b1l[1], b1g[1] + kc);
    async16(b3l[0], b3g[0] + kc); async16(b3l[1], b3g[1] + kc);
    __syncthreads();   // drains vmcnt -> LDS tiles complete

    short8 af[4];
#pragma unroll
    for (int mi = 0; mi < 4; ++mi)
      af[mi] = *(const short8*)&Al[(wm + mi * 16 + ln15) * BK + q * 8];
#pragma unroll
    for (int ni = 0; ni < 4; ++ni) {
      short8 f1 = *(const short8*)&B1l[(wn + ni * 16 + ln15) * BK + q * 8];
      short8 f3 = *(const short8*)&B3l[(wn + ni * 16 + ln15) * BK + q * 8];
#pragma unroll
      for (int mi = 0; mi < 4; ++mi) {
        acc1[mi][ni] = __builtin_amdgcn_mfma_f32_16x16x32_bf16(af[mi], f1, acc1[mi][ni], 0, 0, 0);
        acc3[mi][ni] = __builtin_amdgcn_mfma_f32_16x16x32_bf16(af[mi], f3, acc3[mi][ni], 0, 0, 0);
      }
    }
    __syncthreads();   // all reads done before next overwrite
  }

  // epilogue: h = silu(a1)*a3 -> bf16 H rows (C/D: row=q*4+reg, col=lane&15)
#pragma unroll
  for (int mi = 0; mi < 4; ++mi) {
#pragma unroll
    for (int reg = 0; reg < 4; ++reg) {
      int rg = mt * BM + wm + mi * 16 + q * 4 + reg;
      if (rg < ne) {
        u16* dst = Hbuf + (size_t)(base + rg) * FF + n0 + wn + ln15;
#pragma unroll
        for (int ni = 0; ni < 4; ++ni) {
          float a = acc1[mi][ni][reg];
          float b = acc3[mi][ni][reg];
          float h = (a / (1.0f + __expf(-a))) * b;
          dst[ni * 16] = f2bf(h);
        }
      }
    }
  }
}

// ---------------- GEMM2 (preconverted): Y = H*W2t^T, scatter-add ----------------
__global__ __launch_bounds__(256, 2) void gemm2p_kernel(
    const u16* __restrict__ Hbuf, const u16* __restrict__ wt2,
    const int* __restrict__ stok, const float* __restrict__ sw,
    const int* __restrict__ offsets, const int* __restrict__ counts,
    float* __restrict__ out)
{
  const int e  = blockIdx.z;
  const int mt = blockIdx.y;
  const int ne = counts[e];
  if (mt * BM >= ne) return;
  const int nt = blockIdx.x;
  const int base = offsets[e];
  const u16* __restrict__ W2 = wt2 + (size_t)e * FF * DM;   // [D][F]

  __shared__ u16 Al[BM * BK];
  __shared__ u16 Bl[BN * BK];

  const int tid  = threadIdx.x;
  const int lane = tid & 63;
  const int wv   = tid >> 6;
  const int wm   = (wv & 1) * 64;
  const int wn   = (wv >> 1) * 64;
  const int ln15 = lane & 15;
  const int q    = lane >> 4;
  const int n0   = nt * BN;

  const int rsub = lane >> 2;
  const int seg  = (lane & 3) * 8;

  const u16* ag[2]; const u16* bg[2];
#pragma unroll
  for (int it = 0; it < 2; ++it) {
    int r  = wv * 32 + it * 16 + rsub;
    int rg = mt * BM + r;
    int p  = base + (rg < ne ? rg : 0);
    ag[it] = Hbuf + (size_t)p * FF + seg;
    int n  = n0 + r;
    bg[it] = W2 + (size_t)n * FF + seg;
  }
  u16* al[2] = { Al + (wv * 32) * BK, Al + (wv * 32 + 16) * BK };
  u16* bl[2] = { Bl + (wv * 32) * BK, Bl + (wv * 32 + 16) * BK };

  floatx4 acc[4][4];
#pragma unroll
  for (int mi = 0; mi < 4; ++mi)
#pragma unroll
    for (int ni = 0; ni < 4; ++ni) acc[mi][ni] = (floatx4){0.f, 0.f, 0.f, 0.f};

  for (int kc = 0; kc < FF; kc += BK) {
    async16(al[0], ag[0] + kc); async16(al[1], ag[1] + kc);
    async16(bl[0], bg[0] + kc); async16(bl[1], bg[1] + kc);
    __syncthreads();

    short8 af[4];
#pragma unroll
    for (int mi = 0; mi < 4; ++mi)
      af[mi] = *(const short8*)&Al[(wm + mi * 16 + ln15) * BK + q * 8];
#pragma unroll
    for (int ni = 0; ni < 4; ++ni) {
      short8 bf = *(const short8*)&Bl[(wn + ni * 16 + ln15) * BK + q * 8];
#pragma unroll
      for (int mi = 0; mi < 4; ++mi)
        acc[mi][ni] = __builtin_amdgcn_mfma_f32_16x16x32_bf16(af[mi], bf, acc[mi][ni], 0, 0, 0);
    }
    __syncthreads();
  }

#pragma unroll
  for (int mi = 0; mi < 4; ++mi) {
#pragma unroll
    for (int reg = 0; reg < 4; ++reg) {
      int rg = mt * BM + wm + mi * 16 + q * 4 + reg;
      if (rg < ne) {
        int p = base + rg;
        int tok = stok[p];
        float wgt = sw[p];
        float* dst = out + (size_t)tok * DM + n0 + wn + ln15;
#pragma unroll
        for (int ni = 0; ni < 4; ++ni)
          atomicAdd(&dst[ni * 16], wgt * acc[mi][ni][reg]);
      }
    }
  }
}

// ================= R1 fallback kernels (fused fp32 convert) =================
__global__ __launch_bounds__(256, 2) void gemm1_kernel(
    const u16* __restrict__ xbf, const float* __restrict__ w1, const float* __restrict__ w3,
    const int* __restrict__ stok, const int* __restrict__ offsets,
    const int* __restrict__ counts, u16* __restrict__ Hbuf)
{
  const int e  = blockIdx.z;
  const int mt = blockIdx.y;
  const int ne = counts[e];
  if (mt * BM >= ne) return;
  const int nt = blockIdx.x;
  const int base = offsets[e];
  const float* __restrict__ W1 = w1 + (size_t)e * DM * FF;
  const float* __restrict__ W3 = w3 + (size_t)e * DM * FF;

  __shared__ u16 Al[BM][BK];
  __shared__ u16 B1l[BN][BS];
  __shared__ u16 B3l[BN][BS];

  const int tid  = threadIdx.x;
  const int lane = tid & 63;
  const int wv   = tid >> 6;
  const int wm   = (wv & 1) * 64;
  const int wn   = (wv >> 1) * 64;
  const int ln15 = lane & 15;
  const int q    = lane >> 4;

  const int arow = tid >> 1;
  const int aseg = (tid & 1) * 16;
  const int rg_a = mt * BM + arow;
  const u16* asrc = nullptr;
  if (rg_a < ne) {
    int tok = stok[base + rg_a];
    asrc = xbf + (size_t)tok * DM + aseg;
  }

  const int nb = tid & 127;
  const int kh = (tid >> 7) * 16;
  const int n0 = nt * BN;
  const float* b1p = W1 + (size_t)kh * FF + n0 + nb;
  const float* b3p = W3 + (size_t)kh * FF + n0 + nb;

  floatx4 acc1[4][4], acc3[4][4];
#pragma unroll
  for (int mi = 0; mi < 4; ++mi)
#pragma unroll
    for (int ni = 0; ni < 4; ++ni) {
      acc1[mi][ni] = (floatx4){0.f, 0.f, 0.f, 0.f};
      acc3[mi][ni] = (floatx4){0.f, 0.f, 0.f, 0.f};
    }

  for (int kc = 0; kc < DM; kc += BK) {
    if (asrc) {
      const uint4* s = (const uint4*)(asrc + kc);
      *(uint4*)&Al[arow][aseg]     = s[0];
      *(uint4*)&Al[arow][aseg + 8] = s[1];
    } else {
      uint4 z = {0u, 0u, 0u, 0u};
      *(uint4*)&Al[arow][aseg]     = z;
      *(uint4*)&Al[arow][aseg + 8] = z;
    }
    const float* p1 = b1p + (size_t)kc * FF;
    const float* p3 = b3p + (size_t)kc * FF;
#pragma unroll
    for (int kk = 0; kk < 16; kk += 4) {
      union { u16 s[4]; uint2 u; } v1, v3;
#pragma unroll
      for (int j = 0; j < 4; ++j) {
        v1.s[j] = f2bf(p1[(size_t)(kk + j) * FF]);
        v3.s[j] = f2bf(p3[(size_t)(kk + j) * FF]);
      }
      *(uint2*)&B1l[nb][kh + kk] = v1.u;
      *(uint2*)&B3l[nb][kh + kk] = v3.u;
    }
    __syncthreads();

    short8 af[4];
#pragma unroll
    for (int mi = 0; mi < 4; ++mi)
      af[mi] = *(const short8*)&Al[wm + mi * 16 + ln15][q * 8];
#pragma unroll
    for (int ni = 0; ni < 4; ++ni) {
      short8 b1 = ld_b_frag(&B1l[wn + ni * 16 + ln15][q * 8]);
      short8 b3 = ld_b_frag(&B3l[wn + ni * 16 + ln15][q * 8]);
#pragma unroll
      for (int mi = 0; mi < 4; ++mi) {
        acc1[mi][ni] = __builtin_amdgcn_mfma_f32_16x16x32_bf16(af[mi], b1, acc1[mi][ni], 0, 0, 0);
        acc3[mi][ni] = __builtin_amdgcn_mfma_f32_16x16x32_bf16(af[mi], b3, acc3[mi][ni], 0, 0, 0);
      }
    }
    __syncthreads();
  }

#pragma unroll
  for (int mi = 0; mi < 4; ++mi) {
#pragma unroll
    for (int reg = 0; reg < 4; ++reg) {
      int rg = mt * BM + wm + mi * 16 + q * 4 + reg;
      if (rg < ne) {
        u16* dst = Hbuf + (size_t)(base + rg) * FF + n0 + wn + ln15;
#pragma unroll
        for (int ni = 0; ni < 4; ++ni) {
          float a = acc1[mi][ni][reg];
          float b = acc3[mi][ni][reg];
          float h = (a / (1.0f + __expf(-a))) * b;
          dst[ni * 16] = f2bf(h);
        }
      }
    }
  }
}

__global__ __launch_bounds__(256, 2) void gemm2_kernel(
    const u16* __restrict__ Hbuf, const float* __restrict__ w2,
    const int* __restrict__ stok, const float* __restrict__ sw,
    const int* __restrict__ offsets, const int* __restrict__ counts,
    float* __restrict__ out)
{
  const int e  = blockIdx.z;
  const int mt = blockIdx.y;
  const int ne = counts[e];
  if (mt * BM >= ne) return;
  const int nt = blockIdx.x;
  const int base = offsets[e];
  const float* __restrict__ W2 = w2 + (size_t)e * FF * DM;

  __shared__ u16 Al[BM][BK];
  __shared__ u16 Bl[BN][BS];

  const int tid  = threadIdx.x;
  const int lane = tid & 63;
  const int wv   = tid >> 6;
  const int wm   = (wv & 1) * 64;
  const int wn   = (wv >> 1) * 64;
  const int ln15 = lane & 15;
  const int q    = lane >> 4;

  const int arow = tid >> 1;
  const int aseg = (tid & 1) * 16;
  const int rg_a = mt * BM + arow;
  const u16* asrc = nullptr;
  if (rg_a < ne) asrc = Hbuf + (size_t)(base + rg_a) * FF + aseg;

  const int nb = tid & 127;
  const int kh = (tid >> 7) * 16;
  const int n0 = nt * BN;
  const float* bp = W2 + (size_t)kh * DM + n0 + nb;

  floatx4 acc[4][4];
#pragma unroll
  for (int mi = 0; mi < 4; ++mi)
#pragma unroll
    for (int ni = 0; ni < 4; ++ni) acc[mi][ni] = (floatx4){0.f, 0.f, 0.f, 0.f};

  for (int kc = 0; kc < FF; kc += BK) {
    if (asrc) {
      const uint4* s = (const uint4*)(asrc + kc);
      *(uint4*)&Al[arow][aseg]     = s[0];
      *(uint4*)&Al[arow][aseg + 8] = s[1];
    } else {
      uint4 z = {0u, 0u, 0u, 0u};
      *(uint4*)&Al[arow][aseg]     = z;
      *(uint4*)&Al[arow][aseg + 8] = z;
    }
    const float* p2 = bp + (size_t)kc * DM;
#pragma unroll
    for (int kk = 0; kk < 16; kk += 4) {
      union { u16 s[4]; uint2 u; } v2;
#pragma unroll
      for (int j = 0; j < 4; ++j) v2.s[j] = f2bf(p2[(size_t)(kk + j) * DM]);
      *(uint2*)&Bl[nb][kh + kk] = v2.u;
    }
    __syncthreads();

    short8 af[4];
#pragma unroll
    for (int mi = 0; mi < 4; ++mi)
      af[mi] = *(const short8*)&Al[wm + mi * 16 + ln15][q * 8];
#pragma unroll
    for (int ni = 0; ni < 4; ++ni) {
      short8 b = ld_b_frag(&Bl[wn + ni * 16 + ln15][q * 8]);
#pragma unroll
      for (int mi = 0; mi < 4; ++mi)
        acc[mi][ni] = __builtin_amdgcn_mfma_f32_16x16x32_bf16(af[mi], b, acc[mi][ni], 0, 0, 0);
    }
    __syncthreads();
  }

#pragma unroll
  for (int mi = 0; mi < 4; ++mi) {
#pragma unroll
    for (int reg = 0; reg < 4; ++reg) {
      int rg = mt * BM + wm + mi * 16 + q * 4 + reg;
      if (rg < ne) {
        int p = base + rg;
        int tok = stok[p];
        float wgt = sw[p];
        float* dst = out + (size_t)tok * DM + n0 + wn + ln15;
#pragma unroll
        for (int ni = 0; ni < 4; ++ni)
          atomicAdd(&dst[ni * 16], wgt * acc[mi][ni][reg]);
      }
    }
  }
}

extern "C" void kernel_launch(void* const* d_in, const int* in_sizes, int n_in,
                              void* d_out, int out_size, void* d_ws, size_t ws_size,
                              hipStream_t stream) {
  const float* x  = (const float*)d_in[0];
  const float* gw = (const float*)d_in[1];
  const float* w1 = (const float*)d_in[2];
  const float* w2 = (const float*)d_in[3];
  const float* w3 = (const float*)d_in[4];
  float* out = (float*)d_out;
  char* ws = (char*)d_ws;

  int*   counts  = (int*)(ws + WS_COUNTS);
  int*   cursors = (int*)(ws + WS_CURS);
  int*   offsets = (int*)(ws + WS_OFFS);
  int*   sel     = (int*)(ws + WS_SEL);
  float* selw    = (float*)(ws + WS_SELW);
  int*   stok    = (int*)(ws + WS_STOK);
  float* sw      = (float*)(ws + WS_SW);
  u16*   xbf     = (u16*)(ws + WS_XBF);
  u16*   Hbuf    = (u16*)(ws + WS_HBUF);

  const size_t need_full = (size_t)265 << 20;
  const size_t need_min  = WS_HBUF + (size_t)(T_TOK * 2) * FF * 2;  // ~73 MB
  if (ws_size < need_min) return;

  hipMemsetAsync(ws, 0, 96, stream);
  hipMemsetAsync(d_out, 0, (size_t)T_TOK * DM * sizeof(float), stream);

  gate_kernel<<<T_TOK / 4, 256, 0, stream>>>(x, gw, xbf, sel, selw, counts);
  offsets_kernel<<<1, 64, 0, stream>>>(counts, offsets);
  fill_kernel<<<T_TOK / 256, 256, 0, stream>>>(sel, selw, offsets, cursors, stok, sw);

  if (ws_size >= need_full) {
    u16* Wt1 = (u16*)(ws + WS_WT1);
    u16* Wt3 = (u16*)(ws + WS_WT3);
    u16* Wt2 = (u16*)(ws + WS_WT2);
    convt_kernel<<<dim3(FF / 64, DM / 64, NE), 256, 0, stream>>>(w1, Wt1, DM, FF);
    convt_kernel<<<dim3(FF / 64, DM / 64, NE), 256, 0, stream>>>(w3, Wt3, DM, FF);
    convt_kernel<<<dim3(DM / 64, FF / 64, NE), 256, 0, stream>>>(w2, Wt2, FF, DM);
    gemm1p_kernel<<<dim3(FF / BN, T_TOK / BM, NE), 256, 0, stream>>>(
        xbf, Wt1, Wt3, stok, offsets, counts, Hbuf);
    gemm2p_kernel<<<dim3(DM / BN, T_TOK / BM, NE), 256, 0, stream>>>(
        Hbuf, Wt2, stok, sw, offsets, counts, out);
  } else {
    gemm1_kernel<<<dim3(FF / BN, T_TOK / BM, NE), 256, 0, stream>>>(
        xbf, w1, w3, stok, offsets, counts, Hbuf);
    gemm2_kernel<<<dim3(DM / BN, T_TOK / BM, NE), 256, 0, stream>>>(
        Hbuf, w2, stok, sw, offsets, counts, out);
  }
}

// Round 3
// 849.224 us; speedup vs baseline: 1.2368x; 1.0898x over previous
//
#include <hip/hip_runtime.h>

// MoE top-2, E=8, D=1024, F=4096, T=4096 tokens, fp32 in/out.
// R3: (a) XOR-swizzled LDS segments (kills 8-way ds_read conflicts while
//     keeping global_load_lds), (b) W1/W3 interleaved into one W13 tensor
//     (64 AGPR accumulators -> 3 waves/EU), (c) gemm2 split-K x2 with plain
//     bf16 partial-Y stores + slot-map combine kernel (no atomics).

#define T_TOK 4096
#define DM    1024
#define FF    4096
#define NE    8

#define BM 128
#define BN 128
#define BK 32

typedef unsigned short u16;
typedef short short8 __attribute__((ext_vector_type(8)));
typedef float floatx4 __attribute__((ext_vector_type(4)));

// ---- ws layout (bytes) ----
#define WS_COUNTS  0u
#define WS_CURS    32u
#define WS_OFFS    64u
#define WS_SEL     4096u
#define WS_SELW    (4096u + 32768u)
#define WS_STOK    (4096u + 65536u)
#define WS_SW      (4096u + 98304u)
#define WS_PMAP    (4096u + 131072u)
#define WS_XBF     ((size_t)1 << 20)       // 8 MB (4096 x 1024 bf16)
#define WS_HBUF    ((size_t)9 << 20)       // 64 MB (8192 x 4096 bf16)
#define WS_W13     ((size_t)73 << 20)      // 128 MB bf16 [E][2F][D] interleaved
#define WS_WT2     ((size_t)201 << 20)     // 64 MB bf16 [E][D][F]
#define WS_YBUF    ((size_t)73 << 20)      // 32 MB bf16 [2][8192][1024]; overlaps W13 (dead by gemm2)

__device__ __forceinline__ u16 f2bf(float f) {
  union { float f; unsigned int u; } v; v.f = f;
  unsigned int r = v.u + 0x7fffu + ((v.u >> 16) & 1u);  // RNE
  return (u16)(r >> 16);
}

__device__ __forceinline__ float bf2f(u16 h) {
  union { unsigned int u; float f; } v; v.u = ((unsigned int)h) << 16;
  return v.f;
}

__device__ __forceinline__ void async16(u16* lds, const u16* g) {
  // one wave-instruction: lane i's 16B -> lds_base + i*16 (dest is wave-uniform+lane*16)
  __builtin_amdgcn_global_load_lds(
      (const __attribute__((address_space(1))) unsigned int*)g,
      (__attribute__((address_space(3))) unsigned int*)lds, 16, 0, 0);
}

// ---------------- gate: logits (double accum), top2+softmax, x->bf16 ----------------
__global__ __launch_bounds__(256) void gate_kernel(
    const float* __restrict__ x, const float* __restrict__ gw,
    u16* __restrict__ xbf, int* __restrict__ sel, float* __restrict__ selw,
    int* __restrict__ counts)
{
  const int t = blockIdx.x * 4 + (threadIdx.x >> 6);   // one wave per token
  const int lane = threadIdx.x & 63;
  const float* xr = x + (size_t)t * DM;
  double acc[NE];
#pragma unroll
  for (int e = 0; e < NE; ++e) acc[e] = 0.0;
#pragma unroll 4
  for (int i = 0; i < 16; ++i) {
    const int d = i * 64 + lane;
    const float xv = xr[d];
    xbf[(size_t)t * DM + d] = f2bf(xv);
    const float4* g = (const float4*)(gw + (size_t)d * NE);
    float4 g0 = g[0], g1 = g[1];
    acc[0] += (double)xv * g0.x; acc[1] += (double)xv * g0.y;
    acc[2] += (double)xv * g0.z; acc[3] += (double)xv * g0.w;
    acc[4] += (double)xv * g1.x; acc[5] += (double)xv * g1.y;
    acc[6] += (double)xv * g1.z; acc[7] += (double)xv * g1.w;
  }
#pragma unroll
  for (int off = 32; off >= 1; off >>= 1) {
#pragma unroll
    for (int e = 0; e < NE; ++e) acc[e] += __shfl_xor(acc[e], off, 64);
  }
  if (lane == 0) {
    int i1 = 0; double v1 = acc[0];
#pragma unroll
    for (int e = 1; e < NE; ++e) if (acc[e] > v1) { v1 = acc[e]; i1 = e; }
    int i2 = -1; double v2 = -1e300;
#pragma unroll
    for (int e = 0; e < NE; ++e) if (e != i1 && acc[e] > v2) { v2 = acc[e]; i2 = e; }
    float p1 = 1.0f / (1.0f + expf((float)(v2 - v1)));   // exact 2-way softmax
    sel[t * 2] = i1; sel[t * 2 + 1] = i2;
    selw[t * 2] = p1; selw[t * 2 + 1] = 1.0f - p1;
    atomicAdd(&counts[i1], 1);
    atomicAdd(&counts[i2], 1);
  }
}

__global__ void offsets_kernel(const int* __restrict__ counts, int* __restrict__ offsets) {
  if (threadIdx.x == 0) {
    int s = 0;
#pragma unroll
    for (int e = 0; e < NE; ++e) { offsets[e] = s; s += counts[e]; }
  }
}

__global__ void fill_kernel(const int* __restrict__ sel,
                            const int* __restrict__ offsets, int* __restrict__ cursors,
                            int* __restrict__ stok, int* __restrict__ pmap)
{
  const int t = blockIdx.x * blockDim.x + threadIdx.x;
  if (t >= T_TOK) return;
#pragma unroll
  for (int k = 0; k < 2; ++k) {
    int e = sel[t * 2 + k];
    int pos = atomicAdd(&cursors[e], 1);
    int p = offsets[e] + pos;
    stok[p] = t;
    pmap[t * 2 + k] = p;
  }
}

// ---------------- convt13: w1/w3 fp32 [E][D][F] -> bf16 [E][2F][D], 16-col interleave ----------------
__global__ __launch_bounds__(256) void convt13_kernel(const float* __restrict__ w1,
                                                      const float* __restrict__ w3,
                                                      u16* __restrict__ dst)
{
  __shared__ float tile[64][65];
  const int e = blockIdx.z >> 1;
  const int s = blockIdx.z & 1;                      // 0 -> w1 (even 16-groups), 1 -> w3 (odd)
  const float* src = (s ? w3 : w1) + (size_t)e * DM * FF;
  u16* d = dst + (size_t)e * (2 * FF) * DM;
  const int f0 = blockIdx.x * 64;
  const int k0 = blockIdx.y * 64;
  const int tr = threadIdx.x >> 4;          // 0..15
  const int tc = (threadIdx.x & 15) * 4;    // 0..60
#pragma unroll
  for (int i = 0; i < 64; i += 16) {
    const float4 v = *(const float4*)&src[(size_t)(k0 + tr + i) * FF + f0 + tc];
    tile[tr + i][tc]     = v.x; tile[tr + i][tc + 1] = v.y;
    tile[tr + i][tc + 2] = v.z; tile[tr + i][tc + 3] = v.w;
  }
  __syncthreads();
  const int nbase = f0 * 2 + s * 16;
#pragma unroll
  for (int ii = 0; ii < 64; ii += 16) {
    union { u16 q[4]; uint2 u; } o;
#pragma unroll
    for (int j = 0; j < 4; ++j) o.q[j] = f2bf(tile[tc + j][tr + ii]);
    const int nrow = nbase + ii * 2 + tr;            // i=tr+ii: n' = nbase + (i>>4)*32 + (i&15)
    *(uint2*)&d[(size_t)nrow * DM + k0 + tc] = o.u;
  }
}

// ---------------- convt2: w2 fp32 [E][F][D] -> bf16 [E][D][F] ----------------
__global__ __launch_bounds__(256) void convt2_kernel(const float* __restrict__ src,
                                                     u16* __restrict__ dst)
{
  __shared__ float tile[64][65];
  const int e = blockIdx.z;
  src += (size_t)e * FF * DM;
  dst += (size_t)e * FF * DM;
  const int n0 = blockIdx.x * 64;   // over D
  const int k0 = blockIdx.y * 64;   // over F
  const int tr = threadIdx.x >> 4;
  const int tc = (threadIdx.x & 15) * 4;
#pragma unroll
  for (int i = 0; i < 64; i += 16) {
    const float4 v = *(const float4*)&src[(size_t)(k0 + tr + i) * DM + n0 + tc];
    tile[tr + i][tc]     = v.x; tile[tr + i][tc + 1] = v.y;
    tile[tr + i][tc + 2] = v.z; tile[tr + i][tc + 3] = v.w;
  }
  __syncthreads();
#pragma unroll
  for (int i = 0; i < 64; i += 16) {
    union { u16 q[4]; uint2 u; } o;
#pragma unroll
    for (int j = 0; j < 4; ++j) o.q[j] = f2bf(tile[tc + j][tr + i]);
    *(uint2*)&dst[(size_t)(n0 + tr + i) * FF + k0 + tc] = o.u;
  }
}

// ---------------- GEMM1: H = silu(X*W1^T).*(X*W3^T) via interleaved W13 ----------------
// LDS swizzle: phys 16B segment s of row r holds logical segment s ^ ((r>>1)&3).
__global__ __launch_bounds__(256, 2) void gemm1p_kernel(
    const u16* __restrict__ xbf, const u16* __restrict__ w13,
    const int* __restrict__ stok, const int* __restrict__ offsets,
    const int* __restrict__ counts, u16* __restrict__ Hbuf)
{
  const int e  = blockIdx.z;
  const int mt = blockIdx.y;
  const int ne = counts[e];
  if (mt * BM >= ne) return;
  const int nt = blockIdx.x;
  const int base = offsets[e];
  const u16* __restrict__ W = w13 + (size_t)e * (2 * FF) * DM;

  __shared__ u16 Al[BM * BK];
  __shared__ u16 Bl[BN * BK];

  const int tid  = threadIdx.x;
  const int lane = tid & 63;
  const int wv   = tid >> 6;
  const int wm   = (wv & 1) * 64;
  const int wn   = (wv >> 1) * 64;
  const int ln15 = lane & 15;
  const int q    = lane >> 4;
  const int n0   = nt * BN;

  const int rsub  = lane >> 2;                       // staging row within 16
  const int slog  = (lane & 3) ^ ((rsub >> 1) & 3);  // logical segment this lane fetches
  const int seg   = slog * 8;                        // bf16 elements

  const u16* ag[2]; const u16* bg[2];
#pragma unroll
  for (int it = 0; it < 2; ++it) {
    int r  = wv * 32 + it * 16 + rsub;
    int rg = mt * BM + r;
    int p  = base + (rg < ne ? rg : 0);              // clamp OOB rows
    int tok = stok[p];
    ag[it] = xbf + (size_t)tok * DM + seg;
    bg[it] = W + (size_t)(n0 + r) * DM + seg;
  }
  u16* al[2] = { Al + (wv * 32) * BK, Al + (wv * 32 + 16) * BK };
  u16* bl[2] = { Bl + (wv * 32) * BK, Bl + (wv * 32 + 16) * BK };

  const int swz = (ln15 >> 1) & 3;                   // read-side sigma(row)

  floatx4 acc[4][4];
#pragma unroll
  for (int mi = 0; mi < 4; ++mi)
#pragma unroll
    for (int ni = 0; ni < 4; ++ni) acc[mi][ni] = (floatx4){0.f, 0.f, 0.f, 0.f};

  for (int kc = 0; kc < DM; kc += BK) {
    async16(al[0], ag[0] + kc); async16(al[1], ag[1] + kc);
    async16(bl[0], bg[0] + kc); async16(bl[1], bg[1] + kc);
    __syncthreads();

    short8 af[4];
#pragma unroll
    for (int mi = 0; mi < 4; ++mi)
      af[mi] = *(const short8*)&Al[(wm + mi * 16 + ln15) * BK + ((q ^ swz) * 8)];
#pragma unroll
    for (int ni = 0; ni < 4; ++ni) {
      short8 bf = *(const short8*)&Bl[(wn + ni * 16 + ln15) * BK + ((q ^ swz) * 8)];
#pragma unroll
      for (int mi = 0; mi < 4; ++mi)
        acc[mi][ni] = __builtin_amdgcn_mfma_f32_16x16x32_bf16(af[mi], bf, acc[mi][ni], 0, 0, 0);
    }
    __syncthreads();
  }

  // epilogue: ni pairs (2j = w1 cols, 2j+1 = w3 cols); f-col = (n0+wn)/2 + j*16 + ln15
  const int hbase = (n0 + wn) >> 1;
#pragma unroll
  for (int mi = 0; mi < 4; ++mi) {
#pragma unroll
    for (int reg = 0; reg < 4; ++reg) {
      int rg = mt * BM + wm + mi * 16 + q * 4 + reg;
      if (rg < ne) {
        u16* dst = Hbuf + (size_t)(base + rg) * FF + hbase + ln15;
#pragma unroll
        for (int j = 0; j < 2; ++j) {
          float a = acc[mi][2 * j][reg];
          float b = acc[mi][2 * j + 1][reg];
          float h = (a / (1.0f + __expf(-a))) * b;
          dst[j * 16] = f2bf(h);
        }
      }
    }
  }
}

// ---------------- GEMM2: partial Y = H*W2^T (split-K x2), plain bf16 stores ----------------
__global__ __launch_bounds__(256, 2) void gemm2p_kernel(
    const u16* __restrict__ Hbuf, const u16* __restrict__ wt2,
    const int* __restrict__ offsets, const int* __restrict__ counts,
    u16* __restrict__ Ybuf)
{
  const int e    = blockIdx.z >> 1;
  const int half = blockIdx.z & 1;
  const int mt = blockIdx.y;
  const int ne = counts[e];
  if (mt * BM >= ne) return;
  const int nt = blockIdx.x;
  const int base = offsets[e];
  const u16* __restrict__ W2 = wt2 + (size_t)e * FF * DM;   // [D][F]

  __shared__ u16 Al[BM * BK];
  __shared__ u16 Bl[BN * BK];

  const int tid  = threadIdx.x;
  const int lane = tid & 63;
  const int wv   = tid >> 6;
  const int wm   = (wv & 1) * 64;
  const int wn   = (wv >> 1) * 64;
  const int ln15 = lane & 15;
  const int q    = lane >> 4;
  const int n0   = nt * BN;

  const int rsub = lane >> 2;
  const int slog = (lane & 3) ^ ((rsub >> 1) & 3);
  const int seg  = slog * 8;

  const u16* ag[2]; const u16* bg[2];
#pragma unroll
  for (int it = 0; it < 2; ++it) {
    int r  = wv * 32 + it * 16 + rsub;
    int rg = mt * BM + r;
    int p  = base + (rg < ne ? rg : 0);
    ag[it] = Hbuf + (size_t)p * FF + seg;
    bg[it] = W2 + (size_t)(n0 + r) * FF + seg;
  }
  u16* al[2] = { Al + (wv * 32) * BK, Al + (wv * 32 + 16) * BK };
  u16* bl[2] = { Bl + (wv * 32) * BK, Bl + (wv * 32 + 16) * BK };

  const int swz = (ln15 >> 1) & 3;

  floatx4 acc[4][4];
#pragma unroll
  for (int mi = 0; mi < 4; ++mi)
#pragma unroll
    for (int ni = 0; ni < 4; ++ni) acc[mi][ni] = (floatx4){0.f, 0.f, 0.f, 0.f};

  const int kbeg = half * (FF / 2);
  const int kend = kbeg + FF / 2;
  for (int kc = kbeg; kc < kend; kc += BK) {
    async16(al[0], ag[0] + kc); async16(al[1], ag[1] + kc);
    async16(bl[0], bg[0] + kc); async16(bl[1], bg[1] + kc);
    __syncthreads();

    short8 af[4];
#pragma unroll
    for (int mi = 0; mi < 4; ++mi)
      af[mi] = *(const short8*)&Al[(wm + mi * 16 + ln15) * BK + ((q ^ swz) * 8)];
#pragma unroll
    for (int ni = 0; ni < 4; ++ni) {
      short8 bf = *(const short8*)&Bl[(wn + ni * 16 + ln15) * BK + ((q ^ swz) * 8)];
#pragma unroll
      for (int mi = 0; mi < 4; ++mi)
        acc[mi][ni] = __builtin_amdgcn_mfma_f32_16x16x32_bf16(af[mi], bf, acc[mi][ni], 0, 0, 0);
    }
    __syncthreads();
  }

  u16* Yb = Ybuf + (size_t)half * (2 * T_TOK) * DM;
#pragma unroll
  for (int mi = 0; mi < 4; ++mi) {
#pragma unroll
    for (int reg = 0; reg < 4; ++reg) {
      int rg = mt * BM + wm + mi * 16 + q * 4 + reg;
      if (rg < ne) {
        u16* dst = Yb + (size_t)(base + rg) * DM + n0 + wn + ln15;
#pragma unroll
        for (int ni = 0; ni < 4; ++ni)
          dst[ni * 16] = f2bf(acc[mi][ni][reg]);
      }
    }
  }
}

// ---------------- combine: out[t] = w0*(Y0[p0]+Y1[p0]) + w1*(Y0[p1]+Y1[p1]) ----------------
__global__ __launch_bounds__(256) void combine_kernel(
    const u16* __restrict__ Ybuf, const int* __restrict__ pmap,
    const float* __restrict__ selw, float* __restrict__ out)
{
  const int t = blockIdx.x;
  const int c = threadIdx.x * 4;
  const int p0 = pmap[t * 2], p1 = pmap[t * 2 + 1];
  const float w0 = selw[t * 2], w1 = selw[t * 2 + 1];
  const size_t HALF = (size_t)(2 * T_TOK) * DM;
  const u16* a0 = Ybuf + (size_t)p0 * DM + c;
  const u16* a1 = Ybuf + (size_t)p1 * DM + c;
  union { u16 q[4]; uint2 u; } va0, vb0, va1, vb1;
  va0.u = *(const uint2*)a0;
  vb0.u = *(const uint2*)(a0 + HALF);
  va1.u = *(const uint2*)a1;
  vb1.u = *(const uint2*)(a1 + HALF);
  float4 o;
  float* op = &o.x;
#pragma unroll
  for (int j = 0; j < 4; ++j)
    op[j] = w0 * (bf2f(va0.q[j]) + bf2f(vb0.q[j])) +
            w1 * (bf2f(va1.q[j]) + bf2f(vb1.q[j]));
  *(float4*)&out[(size_t)t * DM + c] = o;
}

extern "C" void kernel_launch(void* const* d_in, const int* in_sizes, int n_in,
                              void* d_out, int out_size, void* d_ws, size_t ws_size,
                              hipStream_t stream) {
  const float* x  = (const float*)d_in[0];
  const float* gw = (const float*)d_in[1];
  const float* w1 = (const float*)d_in[2];
  const float* w2 = (const float*)d_in[3];
  const float* w3 = (const float*)d_in[4];
  float* out = (float*)d_out;
  char* ws = (char*)d_ws;

  int*   counts  = (int*)(ws + WS_COUNTS);
  int*   cursors = (int*)(ws + WS_CURS);
  int*   offsets = (int*)(ws + WS_OFFS);
  int*   sel     = (int*)(ws + WS_SEL);
  float* selw    = (float*)(ws + WS_SELW);
  int*   stok    = (int*)(ws + WS_STOK);
  int*   pmap    = (int*)(ws + WS_PMAP);
  u16*   xbf     = (u16*)(ws + WS_XBF);
  u16*   Hbuf    = (u16*)(ws + WS_HBUF);
  u16*   W13     = (u16*)(ws + WS_W13);
  u16*   Wt2     = (u16*)(ws + WS_WT2);
  u16*   Ybuf    = (u16*)(ws + WS_YBUF);   // overlaps W13 region (W13 dead before gemm2p)

  const size_t need = (size_t)265 << 20;
  if (ws_size < need) return;

  hipMemsetAsync(ws, 0, 96, stream);  // counts + cursors

  gate_kernel<<<T_TOK / 4, 256, 0, stream>>>(x, gw, xbf, sel, selw, counts);
  offsets_kernel<<<1, 64, 0, stream>>>(counts, offsets);
  fill_kernel<<<T_TOK / 256, 256, 0, stream>>>(sel, offsets, cursors, stok, pmap);

  convt13_kernel<<<dim3(FF / 64, DM / 64, NE * 2), 256, 0, stream>>>(w1, w3, W13);
  convt2_kernel<<<dim3(DM / 64, FF / 64, NE), 256, 0, stream>>>(w2, Wt2);

  gemm1p_kernel<<<dim3(2 * FF / BN, T_TOK / BM, NE), 256, 0, stream>>>(
      xbf, W13, stok, offsets, counts, Hbuf);
  gemm2p_kernel<<<dim3(DM / BN, T_TOK / BM, NE * 2), 256, 0, stream>>>(
      Hbuf, Wt2, offsets, counts, Ybuf);
  combine_kernel<<<T_TOK, 256, 0, stream>>>(Ybuf, pmap, selw, out);
}